// Round 4
// baseline (691.319 us; speedup 1.0000x reference)
//
#include <hip/hip_runtime.h>
#include <cstdint>
#include <cstddef>

// Problem constants (from reference)
#define OUT_F 4096
#define IN_F  11008
#define VECD  8
#define NVEC  (OUT_F * IN_F / VECD)   // 5,636,096 vectors
#define VPR   (IN_F / VECD)           // 1376 vectors per output row
#define M_DIM 4096                    // 2*2048 flattened batch*seq
#define N_DIM OUT_F
#define K_DIM IN_F

typedef __attribute__((ext_vector_type(4))) float f32x4;
typedef __attribute__((ext_vector_type(8))) __bf16 bf16x8;
typedef __attribute__((ext_vector_type(4))) unsigned int u32x4;

__device__ inline unsigned short f2bf(float f) {     // RNE
  union { float f; unsigned int u; } v; v.f = f;
  unsigned int u = v.u;
  unsigned int r = u + 0x7FFFu + ((u >> 16) & 1u);
  return (unsigned short)(r >> 16);
}

// ---------------------------------------------------------------------------
// Phase 1: dequant W + cast X -> bf16.  EXACT round-0 kernel (known ~281 µs).
// Experiment history: 4-wide MLP (r6) regressed (+27); split+nt streams (r7)
// helped phase-1 slightly but nt stores cost gemm +72 µs (operands must stay
// L2/L3-resident for the gemm's staging loads).  Plain stores, fused, 1
// vector/thread is the best measured phase-1 config.  Do not re-theorize
// without counter visibility.
// ---------------------------------------------------------------------------
__global__ __launch_bounds__(256) void dequant_cast_kernel(
    const float* __restrict__ x, const int* __restrict__ indices,
    const float* __restrict__ cb, const float* __restrict__ scales,
    unsigned short* __restrict__ xb, unsigned short* __restrict__ wb) {
  int v = blockIdx.x * 256 + threadIdx.x;
  if (v >= NVEC) return;

  int id = indices[v];
  int o  = v / VPR;
  float s = scales[o];

  const f32x4* c = (const f32x4*)(cb + (size_t)id * VECD);
  f32x4 c0 = c[0], c1 = c[1];
  u32x4 w;
  w.x = (unsigned)f2bf(c0.x * s) | ((unsigned)f2bf(c0.y * s) << 16);
  w.y = (unsigned)f2bf(c0.z * s) | ((unsigned)f2bf(c0.w * s) << 16);
  w.z = (unsigned)f2bf(c1.x * s) | ((unsigned)f2bf(c1.y * s) << 16);
  w.w = (unsigned)f2bf(c1.z * s) | ((unsigned)f2bf(c1.w * s) << 16);
  *(u32x4*)(wb + (size_t)v * 8) = w;

  const f32x4* xp = (const f32x4*)(x + (size_t)v * 8);
  f32x4 x0 = xp[0], x1 = xp[1];
  u32x4 q;
  q.x = (unsigned)f2bf(x0.x) | ((unsigned)f2bf(x0.y) << 16);
  q.y = (unsigned)f2bf(x0.z) | ((unsigned)f2bf(x0.w) << 16);
  q.z = (unsigned)f2bf(x1.x) | ((unsigned)f2bf(x1.y) << 16);
  q.w = (unsigned)f2bf(x1.z) | ((unsigned)f2bf(x1.w) << 16);
  *(u32x4*)(xb + (size_t)v * 8) = q;
}

// ---------------------------------------------------------------------------
// Phase 2: C[M,N] = A[M,K] * B[N,K]^T (bf16, K-contiguous; fp32 out)
//
// Round-8 change: 256x128 tile (was 256x256) -> LDS 3x24 KB = 72 KB ->
// **2 blocks/CU** (was 1).  Mechanism: at 1 block/CU all 8 waves stall
// together at the per-iter vmcnt+barrier (Occupancy 21%, MfmaUtil 47%,
// VALUBusy 19%, conflicts 0 => ~35% synchronized-stall cycles).  Two
// barrier-independent blocks per CU let one block's MFMA cover the other's
// stall (m114 implicit overlap).  Structure is UNCHANGED from the verified
// round-0 kernel (same staging pattern, same XOR swizzle, same 3-buffer
// rotation, same counted-vmcnt discipline — now vmcnt(3) since 3 GLD16/iter).
// Wave-tile 64x64 (4 M-waves x 2 N-waves), acc[4][4].
// Known-failed alternatives: m201-style 2-phase graft (r5: −17 µs, barriers
// removed compiler's fine lgkmcnt scheduling); nt stores on operands (r7:
// +72 µs, residency loss).
// ---------------------------------------------------------------------------
#define GLD16(g, l)                                                     \
  __builtin_amdgcn_global_load_lds(                                     \
      (const __attribute__((address_space(1))) void*)(g),               \
      (__attribute__((address_space(3))) void*)(l), 16, 0, 0)

__global__ __launch_bounds__(512, 4) void gemm_bt_kernel(
    const unsigned short* __restrict__ A,   // M x K bf16 (X)
    const unsigned short* __restrict__ B,   // N x K bf16 (W)
    float* __restrict__ C) {                // M x N fp32
  extern __shared__ unsigned short SMEM[];  // 3*(8192+4096)*2B = 72 KB
  unsigned short* SA = SMEM;                // [3][8192]  (256 rows x 32)
  unsigned short* SB = SMEM + 3 * 8192;     // [3][4096]  (128 rows x 32)

  const int tid  = threadIdx.x;
  const int bm   = blockIdx.x >> 5;         // 0..15  (M/256)
  const int bn   = blockIdx.x & 31;         // 0..31  (N/128)
  const int lane = tid & 63;
  const int wave = tid >> 6;                // 0..7
  const int wm   = (wave & 3) * 64;         // 4 waves in M: 0,64,128,192
  const int wn   = (wave >> 2) * 64;        // 2 waves in N: 0,64
  const int lrow = lane & 15;
  const int kgrp = lane >> 4;
  const int kslot = (kgrp ^ ((lrow >> 1) & 3)) * 8;

  // Staging: thread t owns LDS slot (row = t>>2, chunk cs = t&3); fetches
  // global chunk cs^((row>>1)&3).  A: rows srow and srow+128 (2 GLD16);
  // B: rows 0..127 exactly once (1 GLD16).  3 GLD16/thread/iter = 24 KB.
  const int srow = tid >> 2;                // 0..127
  const int cg   = (tid & 3) ^ ((srow >> 1) & 3);
  const unsigned short* a0 = A + (size_t)(bm * 256 + srow) * K_DIM + cg * 8;
  const unsigned short* a1 = a0 + (size_t)128 * K_DIM;
  const unsigned short* b0 = B + (size_t)(bn * 128 + srow) * K_DIM + cg * 8;
  const int l0 = tid * 8;                   // A rows 0..127 region / all of B
  const int l1 = 4096 + tid * 8;            // A rows 128..255 region

#define STAGE(pbuf, kf)                                   \
  do {                                                    \
    GLD16(a0 + (kf), &SA[(pbuf) * 8192 + l0]);            \
    GLD16(a1 + (kf), &SA[(pbuf) * 8192 + l1]);            \
    GLD16(b0 + (kf), &SB[(pbuf) * 4096 + l0]);            \
  } while (0)

  f32x4 acc[4][4];
#pragma unroll
  for (int i = 0; i < 4; i++)
#pragma unroll
    for (int j = 0; j < 4; j++) acc[i][j] = f32x4{0.f, 0.f, 0.f, 0.f};

  STAGE(0, 0);                              // tile 0 -> buf 0
  STAGE(1, 32);                             // tile 1 -> buf 1
  int cbuf = 0, pbuf = 2;

  for (int k0 = 0; k0 < K_DIM; k0 += 32) {
    // Wait for the OLDEST 3 loads (this iter's tile); keep newest 3 flying.
    asm volatile("s_waitcnt vmcnt(3)\n\ts_barrier" ::: "memory");

    int kf = k0 + 64;                       // prefetch tile k+2 (clamped tail)
    if (kf > K_DIM - 32) kf = K_DIM - 32;
    STAGE(pbuf, kf);

    bf16x8 af[4], bfr[4];
#pragma unroll
    for (int i = 0; i < 4; i++)
      af[i] = *(const bf16x8*)&SA[cbuf * 8192 + (wm + i * 16 + lrow) * 32 + kslot];
#pragma unroll
    for (int j = 0; j < 4; j++)
      bfr[j] = *(const bf16x8*)&SB[cbuf * 4096 + (wn + j * 16 + lrow) * 32 + kslot];

#pragma unroll
    for (int i = 0; i < 4; i++)
#pragma unroll
      for (int j = 0; j < 4; j++)
        acc[i][j] = __builtin_amdgcn_mfma_f32_16x16x32_bf16(
            af[i], bfr[j], acc[i][j], 0, 0, 0);

    cbuf = (cbuf == 2) ? 0 : cbuf + 1;
    pbuf = (pbuf == 2) ? 0 : pbuf + 1;
  }
#undef STAGE

  // Epilogue: C/D layout col = lane&15, row = (lane>>4)*4 + reg  [m89-verified]
#pragma unroll
  for (int i = 0; i < 4; i++) {
    const int row0 = bm * 256 + wm + i * 16 + kgrp * 4;
#pragma unroll
    for (int j = 0; j < 4; j++) {
      const int col = bn * 128 + wn + j * 16 + lrow;
#pragma unroll
      for (int r = 0; r < 4; r++)
        C[(size_t)(row0 + r) * N_DIM + col] = acc[i][j][r];
    }
  }
}

// ---------------------------------------------------------------------------
// Fallback (only if workspace is too small for the bf16 operands).
// ---------------------------------------------------------------------------
__global__ __launch_bounds__(256) void naive_kernel(
    const float* __restrict__ x, const int* __restrict__ indices,
    const float* __restrict__ cb, const float* __restrict__ scales,
    float* __restrict__ out) {
  int n = blockIdx.x * 256 + threadIdx.x;
  int m = blockIdx.y;
  if (n >= N_DIM) return;
  float s = scales[n];
  const float* xr = x + (size_t)m * IN_F;
  const int* ir = indices + (size_t)n * VPR;
  float acc = 0.f;
  for (int v = 0; v < VPR; v++) {
    int id = ir[v];
    const float* c = cb + (size_t)id * 8;
#pragma unroll
    for (int e = 0; e < 8; e++) acc += xr[v * 8 + e] * c[e];
  }
  out[(size_t)m * N_DIM + n] = acc * s;
}

extern "C" void kernel_launch(void* const* d_in, const int* in_sizes, int n_in,
                              void* d_out, int out_size, void* d_ws, size_t ws_size,
                              hipStream_t stream) {
  const float* x       = (const float*)d_in[0];   // (2,2048,11008) fp32
  const int*   indices = (const int*)d_in[1];     // (5636096,) int32
  const float* cb      = (const float*)d_in[2];   // (32768,8) fp32
  const float* scales  = (const float*)d_in[3];   // (4096,1) fp32
  float* out = (float*)d_out;                     // (2,2048,4096) fp32

  const size_t xb_elems = (size_t)M_DIM * K_DIM;  // 45,088,768
  const size_t wb_elems = (size_t)N_DIM * K_DIM;  // 45,088,768
  const size_t need = (xb_elems + wb_elems) * sizeof(unsigned short); // ~172 MB

  if (ws_size >= need) {
    unsigned short* xb = (unsigned short*)d_ws;
    unsigned short* wb = xb + xb_elems;
    dequant_cast_kernel<<<NVEC / 256, 256, 0, stream>>>(x, indices, cb, scales,
                                                        xb, wb);
    gemm_bt_kernel<<<(M_DIM / 256) * (N_DIM / 128), 512,
                     3 * (8192 + 4096) * 2, stream>>>(xb, wb, out);
  } else {
    naive_kernel<<<dim3(N_DIM / 256, M_DIM), 256, 0, stream>>>(x, indices, cb,
                                                               scales, out);
  }
}

// Round 6
// 640.239 us; speedup vs baseline: 1.0798x; 1.0798x over previous
//
#include <hip/hip_runtime.h>
#include <cstdint>
#include <cstddef>

// Problem constants (from reference)
#define OUT_F 4096
#define IN_F  11008
#define VECD  8
#define NVEC  (OUT_F * IN_F / VECD)   // 5,636,096 vectors
#define VPR   (IN_F / VECD)           // 1376 vectors per output row
#define M_DIM 4096                    // 2*2048 flattened batch*seq
#define N_DIM OUT_F
#define K_DIM IN_F

typedef __attribute__((ext_vector_type(4))) float f32x4;
typedef __attribute__((ext_vector_type(8))) __bf16 bf16x8;
typedef __attribute__((ext_vector_type(4))) unsigned int u32x4;

__device__ inline unsigned short f2bf(float f) {     // RNE
  union { float f; unsigned int u; } v; v.f = f;
  unsigned int u = v.u;
  unsigned int r = u + 0x7FFFu + ((u >> 16) & 1u);
  return (unsigned short)(r >> 16);
}

// ---------------------------------------------------------------------------
// Phase 1: dequant W + cast X -> bf16.  EXACT round-0 kernel (known ~281 µs,
// best measured).  Failed experiments: 4-wide MLP (+27 µs), split+nt streams
// (phase-1 −13 µs but gemm +72 µs from operand-residency loss).  Leave alone.
// ---------------------------------------------------------------------------
__global__ __launch_bounds__(256) void dequant_cast_kernel(
    const float* __restrict__ x, const int* __restrict__ indices,
    const float* __restrict__ cb, const float* __restrict__ scales,
    unsigned short* __restrict__ xb, unsigned short* __restrict__ wb) {
  int v = blockIdx.x * 256 + threadIdx.x;
  if (v >= NVEC) return;

  int id = indices[v];
  int o  = v / VPR;
  float s = scales[o];

  const f32x4* c = (const f32x4*)(cb + (size_t)id * VECD);
  f32x4 c0 = c[0], c1 = c[1];
  u32x4 w;
  w.x = (unsigned)f2bf(c0.x * s) | ((unsigned)f2bf(c0.y * s) << 16);
  w.y = (unsigned)f2bf(c0.z * s) | ((unsigned)f2bf(c0.w * s) << 16);
  w.z = (unsigned)f2bf(c1.x * s) | ((unsigned)f2bf(c1.y * s) << 16);
  w.w = (unsigned)f2bf(c1.z * s) | ((unsigned)f2bf(c1.w * s) << 16);
  *(u32x4*)(wb + (size_t)v * 8) = w;

  const f32x4* xp = (const f32x4*)(x + (size_t)v * 8);
  f32x4 x0 = xp[0], x1 = xp[1];
  u32x4 q;
  q.x = (unsigned)f2bf(x0.x) | ((unsigned)f2bf(x0.y) << 16);
  q.y = (unsigned)f2bf(x0.z) | ((unsigned)f2bf(x0.w) << 16);
  q.z = (unsigned)f2bf(x1.x) | ((unsigned)f2bf(x1.y) << 16);
  q.w = (unsigned)f2bf(x1.z) | ((unsigned)f2bf(x1.w) << 16);
  *(u32x4*)(xb + (size_t)v * 8) = q;
}

// ---------------------------------------------------------------------------
// Phase 2: C[M,N] = A[M,K] * B[N,K]^T (bf16, K-contiguous; fp32 out)
//
// Round-9/10: SAME 256x256 tile / 3-buffer / BK=32 / counted-vmcnt /
// XOR-swizzle structure as the 342 µs baseline, but **16 waves (1024 thr)**
// instead of 8.  (Round-9 bench died to an infra failure — "container failed
// twice", no compile/run evidence — so this is an identical re-run.)
// Rationale from r8's counters: feed volume is the hard wall (256x128 raised
// feed 2.88->4.2 GB and hit the ~10.2 TB/s feed ceiling = measured 414 µs),
// and REGISTERS (not LDS) capped 256² at one 8-wave block: acc[8][4]=128
// AGPR + 92 VGPR ~ 220/wave -> 9 waves/CU max.  16 waves of wave-tile 64x64
// need only acc[4][4]=64 AGPR + ~56 VGPR ~ 120 <= 128/wave (r8 measured 56
// VGPR at this acc size), so one 1024-thread block = 4 waves/SIMD (2x the
// contexts) at UNCHANGED feed volume.
// Per-thread staging halves: 2 GLD16/iter (1 A + 1 B) -> vmcnt(2).
// Known-failed: m201 2-phase graft (r5), nt stores (r7), 256x128 (r8).
// ---------------------------------------------------------------------------
#define GLD16(g, l)                                                     \
  __builtin_amdgcn_global_load_lds(                                     \
      (const __attribute__((address_space(1))) void*)(g),               \
      (__attribute__((address_space(3))) void*)(l), 16, 0, 0)

__global__ __launch_bounds__(1024, 4) void gemm_bt_kernel(
    const unsigned short* __restrict__ A,   // M x K bf16 (X)
    const unsigned short* __restrict__ B,   // N x K bf16 (W)
    float* __restrict__ C) {                // M x N fp32
  extern __shared__ unsigned short SMEM[];  // 3*(8192+8192)*2B = 96 KB
  unsigned short* SA = SMEM;                // [3][8192]  (256 rows x 32)
  unsigned short* SB = SMEM + 3 * 8192;     // [3][8192]  (256 rows x 32)

  const int tid  = threadIdx.x;
  const int bm   = blockIdx.x >> 4;         // 0..15
  const int bn   = blockIdx.x & 15;         // 0..15
  const int lane = tid & 63;
  const int wave = tid >> 6;                // 0..15
  const int wm   = (wave & 3) * 64;         // 4 waves in M: 0,64,128,192
  const int wn   = (wave >> 2) * 64;        // 4 waves in N: 0,64,128,192
  const int lrow = lane & 15;
  const int kgrp = lane >> 4;
  const int kslot = (kgrp ^ ((lrow >> 1) & 3)) * 8;

  // Staging: 1024 threads, 2 GLD16 each = 32 KB/iter.  Thread t owns LDS
  // slot (row = t>>2, chunk cs = t&3) in BOTH SA and SB; fetches global
  // chunk cs^((row>>1)&3) — identical swizzle math to the verified baseline
  // (rows 0..255 directly; the XOR term depends only on (row>>1)&3).
  const int srow = tid >> 2;                // 0..255
  const int cg   = (tid & 3) ^ ((srow >> 1) & 3);
  const unsigned short* a0 = A + (size_t)(bm * 256 + srow) * K_DIM + cg * 8;
  const unsigned short* b0 = B + (size_t)(bn * 256 + srow) * K_DIM + cg * 8;
  const int l0 = tid * 8;                   // covers all 256 rows (16KB)

#define STAGE(pbuf, kf)                                   \
  do {                                                    \
    GLD16(a0 + (kf), &SA[(pbuf) * 8192 + l0]);            \
    GLD16(b0 + (kf), &SB[(pbuf) * 8192 + l0]);            \
  } while (0)

  f32x4 acc[4][4];
#pragma unroll
  for (int i = 0; i < 4; i++)
#pragma unroll
    for (int j = 0; j < 4; j++) acc[i][j] = f32x4{0.f, 0.f, 0.f, 0.f};

  STAGE(0, 0);                              // tile 0 -> buf 0
  STAGE(1, 32);                             // tile 1 -> buf 1
  int cbuf = 0, pbuf = 2;

  for (int k0 = 0; k0 < K_DIM; k0 += 32) {
    // Wait for the OLDEST 2 loads (this iter's tile); keep newest 2 flying.
    asm volatile("s_waitcnt vmcnt(2)\n\ts_barrier" ::: "memory");

    int kf = k0 + 64;                       // prefetch tile k+2 (clamped tail)
    if (kf > K_DIM - 32) kf = K_DIM - 32;
    STAGE(pbuf, kf);

    bf16x8 af[4], bfr[4];
#pragma unroll
    for (int i = 0; i < 4; i++)
      af[i] = *(const bf16x8*)&SA[cbuf * 8192 + (wm + i * 16 + lrow) * 32 + kslot];
#pragma unroll
    for (int j = 0; j < 4; j++)
      bfr[j] = *(const bf16x8*)&SB[cbuf * 8192 + (wn + j * 16 + lrow) * 32 + kslot];

#pragma unroll
    for (int i = 0; i < 4; i++)
#pragma unroll
      for (int j = 0; j < 4; j++)
        acc[i][j] = __builtin_amdgcn_mfma_f32_16x16x32_bf16(
            af[i], bfr[j], acc[i][j], 0, 0, 0);

    cbuf = (cbuf == 2) ? 0 : cbuf + 1;
    pbuf = (pbuf == 2) ? 0 : pbuf + 1;
  }
#undef STAGE

  // Epilogue: C/D layout col = lane&15, row = (lane>>4)*4 + reg  [m89-verified]
#pragma unroll
  for (int i = 0; i < 4; i++) {
    const int row0 = bm * 256 + wm + i * 16 + kgrp * 4;
#pragma unroll
    for (int j = 0; j < 4; j++) {
      const int col = bn * 256 + wn + j * 16 + lrow;
#pragma unroll
      for (int r = 0; r < 4; r++)
        C[(size_t)(row0 + r) * N_DIM + col] = acc[i][j][r];
    }
  }
}

// ---------------------------------------------------------------------------
// Fallback (only if workspace is too small for the bf16 operands).
// ---------------------------------------------------------------------------
__global__ __launch_bounds__(256) void naive_kernel(
    const float* __restrict__ x, const int* __restrict__ indices,
    const float* __restrict__ cb, const float* __restrict__ scales,
    float* __restrict__ out) {
  int n = blockIdx.x * 256 + threadIdx.x;
  int m = blockIdx.y;
  if (n >= N_DIM) return;
  float s = scales[n];
  const float* xr = x + (size_t)m * IN_F;
  const int* ir = indices + (size_t)n * VPR;
  float acc = 0.f;
  for (int v = 0; v < VPR; v++) {
    int id = ir[v];
    const float* c = cb + (size_t)id * 8;
#pragma unroll
    for (int e = 0; e < 8; e++) acc += xr[v * 8 + e] * c[e];
  }
  out[(size_t)m * N_DIM + n] = acc * s;
}

extern "C" void kernel_launch(void* const* d_in, const int* in_sizes, int n_in,
                              void* d_out, int out_size, void* d_ws, size_t ws_size,
                              hipStream_t stream) {
  const float* x       = (const float*)d_in[0];   // (2,2048,11008) fp32
  const int*   indices = (const int*)d_in[1];     // (5636096,) int32
  const float* cb      = (const float*)d_in[2];   // (32768,8) fp32
  const float* scales  = (const float*)d_in[3];   // (4096,1) fp32
  float* out = (float*)d_out;                     // (2,2048,4096) fp32

  const size_t xb_elems = (size_t)M_DIM * K_DIM;  // 45,088,768
  const size_t wb_elems = (size_t)N_DIM * K_DIM;  // 45,088,768
  const size_t need = (xb_elems + wb_elems) * sizeof(unsigned short); // ~172 MB

  if (ws_size >= need) {
    unsigned short* xb = (unsigned short*)d_ws;
    unsigned short* wb = xb + xb_elems;
    dequant_cast_kernel<<<NVEC / 256, 256, 0, stream>>>(x, indices, cb, scales,
                                                        xb, wb);
    gemm_bt_kernel<<<(M_DIM / 256) * (N_DIM / 256), 1024, 6 * 8192 * 2, stream>>>(
        xb, wb, out);
  } else {
    naive_kernel<<<dim3(N_DIM / 256, M_DIM), 256, 0, stream>>>(x, indices, cb,
                                                               scales, out);
  }
}

// Round 7
// 638.608 us; speedup vs baseline: 1.0825x; 1.0026x over previous
//
#include <hip/hip_runtime.h>
#include <cstdint>
#include <cstddef>

// Problem constants (from reference)
#define OUT_F 4096
#define IN_F  11008
#define VECD  8
#define NVEC  (OUT_F * IN_F / VECD)   // 5,636,096 vectors
#define VPR   (IN_F / VECD)           // 1376 vectors per output row
#define NCODES 32768
#define M_DIM 4096                    // 2*2048 flattened batch*seq
#define N_DIM OUT_F
#define K_DIM IN_F

typedef __attribute__((ext_vector_type(4))) float f32x4;
typedef __attribute__((ext_vector_type(8))) __bf16 bf16x8;
typedef __attribute__((ext_vector_type(4))) unsigned int u32x4;

__device__ inline unsigned short f2bf(float f) {     // RNE
  union { float f; unsigned int u; } v; v.f = f;
  unsigned int u = v.u;
  unsigned int r = u + 0x7FFFu + ((u >> 16) & 1u);
  return (unsigned short)(r >> 16);
}

// ---------------------------------------------------------------------------
// Phase 0: pre-cast codebook fp32 -> bf16 once (32768 vectors, 512 KB out).
// Enables the scale-factored scheme: C = s[n] * (X @ W0^T), W0 = cb[idx],
// so the per-vector dequant becomes a pure 16-B gather-copy (below) and the
// scale is applied in the GEMM epilogue in fp32.
// ---------------------------------------------------------------------------
__global__ __launch_bounds__(256) void cbcast_kernel(
    const float* __restrict__ cb, unsigned short* __restrict__ cbb) {
  int i = blockIdx.x * 256 + threadIdx.x;   // one codebook vector per thread
  if (i >= NCODES) return;
  const f32x4* c = (const f32x4*)(cb + (size_t)i * VECD);
  f32x4 c0 = c[0], c1 = c[1];
  u32x4 w;
  w.x = (unsigned)f2bf(c0.x) | ((unsigned)f2bf(c0.y) << 16);
  w.y = (unsigned)f2bf(c0.z) | ((unsigned)f2bf(c0.w) << 16);
  w.z = (unsigned)f2bf(c1.x) | ((unsigned)f2bf(c1.y) << 16);
  w.w = (unsigned)f2bf(c1.z) | ((unsigned)f2bf(c1.w) << 16);
  *(u32x4*)(cbb + (size_t)i * 8) = w;
}

// ---------------------------------------------------------------------------
// Phase 1: W gather-copy + X cast -> bf16.  Round-11: scale factored out.
// W-half is now {4B idx load, ONE 16B gather from the 512KB bf16 codebook,
// 16B store} — gather instrs halved (2->1), gather bytes halved, zero VALU
// (no f2bf, no scale mul, no scales load, no v/VPR division).  X-half is the
// unchanged r0-proven code.  This doubles as the cleanest probe of phase-1's
// unexplained ~210 µs w-cost: if it scales with gather count/width this drops
// ~60-90 µs; if unchanged, gather width/VALU are exonerated.
// Failed history: 4-wide MLP (+27 µs), nt streams (gemm +72, residency loss).
// ---------------------------------------------------------------------------
__global__ __launch_bounds__(256) void dequant_cast_kernel(
    const float* __restrict__ x, const int* __restrict__ indices,
    const unsigned short* __restrict__ cbb, unsigned short* __restrict__ xb,
    unsigned short* __restrict__ wb) {
  int v = blockIdx.x * 256 + threadIdx.x;
  if (v >= NVEC) return;

  int id = indices[v];
  u32x4 w = *(const u32x4*)(cbb + (size_t)id * 8);   // single 16B gather
  *(u32x4*)(wb + (size_t)v * 8) = w;

  const f32x4* xp = (const f32x4*)(x + (size_t)v * 8);
  f32x4 x0 = xp[0], x1 = xp[1];
  u32x4 q;
  q.x = (unsigned)f2bf(x0.x) | ((unsigned)f2bf(x0.y) << 16);
  q.y = (unsigned)f2bf(x0.z) | ((unsigned)f2bf(x0.w) << 16);
  q.z = (unsigned)f2bf(x1.x) | ((unsigned)f2bf(x1.y) << 16);
  q.w = (unsigned)f2bf(x1.z) | ((unsigned)f2bf(x1.w) << 16);
  *(u32x4*)(xb + (size_t)v * 8) = q;
}

// ---------------------------------------------------------------------------
// Phase 2: C[M,N] = s[n] * (A[M,K] * B0[N,K]^T)  (bf16 operands, fp32 out)
//
// EXACT round-0 kernel (proven 342-356 µs, MfmaUtil 47%, 0 conflicts) plus a
// per-column scale in the epilogue (4 scalar loads + 16 muls/thread).
// Structure findings, settled: 2-phase graft −17 µs (r5); nt stores +72 µs
// (r7); 256x128 +74 µs (feed 2.88->4.2 GB, r8); 16-wave 1024-thr +5 µs
// (LDS-read redundancy 96->128 KB/K-step at unchanged bytes/FLOP, r10).
// Pipe budget says the loop is LDS/feed-throughput limited; only the full
// m201 BK=64 deep-pipeline port would move it — out of scope this round.
// ---------------------------------------------------------------------------
#define GLD16(g, l)                                                     \
  __builtin_amdgcn_global_load_lds(                                     \
      (const __attribute__((address_space(1))) void*)(g),               \
      (__attribute__((address_space(3))) void*)(l), 16, 0, 0)

__global__ __launch_bounds__(512, 2) void gemm_bt_kernel(
    const unsigned short* __restrict__ A,   // M x K bf16 (X)
    const unsigned short* __restrict__ B,   // N x K bf16 (W0, unscaled)
    const float* __restrict__ S,            // N fp32 row scales
    float* __restrict__ C) {                // M x N fp32
  extern __shared__ unsigned short SMEM[];  // 3*(8192+8192) = 96 KB
  unsigned short* SA = SMEM;                // [3][8192]
  unsigned short* SB = SMEM + 3 * 8192;     // [3][8192]

  const int tid  = threadIdx.x;
  const int bm   = blockIdx.x >> 4;         // 0..15
  const int bn   = blockIdx.x & 15;         // 0..15
  const int lane = tid & 63;
  const int wave = tid >> 6;                // 0..7
  const int wm   = (wave & 1) * 128;        // 2 waves in M
  const int wn   = (wave >> 1) * 64;        // 4 waves in N
  const int lrow = lane & 15;
  const int kgrp = lane >> 4;
  const int kslot = (kgrp ^ ((lrow >> 1) & 3)) * 8;

  // Staging: 512 threads, 4 GLD16 each = 32 KB/iter. Thread t owns LDS slot
  // (row = t>>2 [+128], chunk cs = t&3); fetches global chunk cs^((row>>1)&3)
  // (same XOR term for row+128 since 128/2 ≡ 0 mod 4).
  const int srow = tid >> 2;                // 0..127
  const int cg   = (tid & 3) ^ ((srow >> 1) & 3);
  const unsigned short* a0 = A + (size_t)(bm * 256 + srow) * K_DIM + cg * 8;
  const unsigned short* a1 = a0 + (size_t)128 * K_DIM;
  const unsigned short* b0 = B + (size_t)(bn * 256 + srow) * K_DIM + cg * 8;
  const unsigned short* b1 = b0 + (size_t)128 * K_DIM;
  const int l0 = tid * 8;                   // rows 0..127 region
  const int l1 = 4096 + tid * 8;            // rows 128..255 region

#define STAGE(pbuf, kf)                                   \
  do {                                                    \
    GLD16(a0 + (kf), &SA[(pbuf) * 8192 + l0]);            \
    GLD16(a1 + (kf), &SA[(pbuf) * 8192 + l1]);            \
    GLD16(b0 + (kf), &SB[(pbuf) * 8192 + l0]);            \
    GLD16(b1 + (kf), &SB[(pbuf) * 8192 + l1]);            \
  } while (0)

  f32x4 acc[8][4];
#pragma unroll
  for (int i = 0; i < 8; i++)
#pragma unroll
    for (int j = 0; j < 4; j++) acc[i][j] = f32x4{0.f, 0.f, 0.f, 0.f};

  STAGE(0, 0);                              // tile 0 -> buf 0
  STAGE(1, 32);                             // tile 1 -> buf 1
  int cbuf = 0, pbuf = 2;

  for (int k0 = 0; k0 < K_DIM; k0 += 32) {
    // Wait for the OLDEST 4 loads (this iter's tile); keep newest 4 flying.
    asm volatile("s_waitcnt vmcnt(4)\n\ts_barrier" ::: "memory");

    int kf = k0 + 64;                       // prefetch tile k+2 (clamped tail)
    if (kf > K_DIM - 32) kf = K_DIM - 32;
    STAGE(pbuf, kf);

    bf16x8 af[8], bfr[4];
#pragma unroll
    for (int i = 0; i < 8; i++)
      af[i] = *(const bf16x8*)&SA[cbuf * 8192 + (wm + i * 16 + lrow) * 32 + kslot];
#pragma unroll
    for (int j = 0; j < 4; j++)
      bfr[j] = *(const bf16x8*)&SB[cbuf * 8192 + (wn + j * 16 + lrow) * 32 + kslot];

#pragma unroll
    for (int i = 0; i < 8; i++)
#pragma unroll
      for (int j = 0; j < 4; j++)
        acc[i][j] = __builtin_amdgcn_mfma_f32_16x16x32_bf16(
            af[i], bfr[j], acc[i][j], 0, 0, 0);

    cbuf = (cbuf == 2) ? 0 : cbuf + 1;
    pbuf = (pbuf == 2) ? 0 : pbuf + 1;
  }
#undef STAGE

  // Epilogue: C/D layout col = lane&15, row = (lane>>4)*4 + reg [m89-verified]
  // plus the factored-out per-column (output-row n) scale, applied in fp32.
  float sj[4];
#pragma unroll
  for (int j = 0; j < 4; j++)
    sj[j] = S[bn * 256 + wn + j * 16 + lrow];

#pragma unroll
  for (int i = 0; i < 8; i++) {
    const int row0 = bm * 256 + wm + i * 16 + kgrp * 4;
#pragma unroll
    for (int j = 0; j < 4; j++) {
      const int col = bn * 256 + wn + j * 16 + lrow;
#pragma unroll
      for (int r = 0; r < 4; r++)
        C[(size_t)(row0 + r) * N_DIM + col] = acc[i][j][r] * sj[j];
    }
  }
}

// ---------------------------------------------------------------------------
// Fallback (only if workspace is too small for the bf16 operands).
// ---------------------------------------------------------------------------
__global__ __launch_bounds__(256) void naive_kernel(
    const float* __restrict__ x, const int* __restrict__ indices,
    const float* __restrict__ cb, const float* __restrict__ scales,
    float* __restrict__ out) {
  int n = blockIdx.x * 256 + threadIdx.x;
  int m = blockIdx.y;
  if (n >= N_DIM) return;
  float s = scales[n];
  const float* xr = x + (size_t)m * IN_F;
  const int* ir = indices + (size_t)n * VPR;
  float acc = 0.f;
  for (int v = 0; v < VPR; v++) {
    int id = ir[v];
    const float* c = cb + (size_t)id * 8;
#pragma unroll
    for (int e = 0; e < 8; e++) acc += xr[v * 8 + e] * c[e];
  }
  out[(size_t)m * N_DIM + n] = acc * s;
}

extern "C" void kernel_launch(void* const* d_in, const int* in_sizes, int n_in,
                              void* d_out, int out_size, void* d_ws, size_t ws_size,
                              hipStream_t stream) {
  const float* x       = (const float*)d_in[0];   // (2,2048,11008) fp32
  const int*   indices = (const int*)d_in[1];     // (5636096,) int32
  const float* cb      = (const float*)d_in[2];   // (32768,8) fp32
  const float* scales  = (const float*)d_in[3];   // (4096,1) fp32
  float* out = (float*)d_out;                     // (2,2048,4096) fp32

  const size_t xb_elems  = (size_t)M_DIM * K_DIM;  // 45,088,768
  const size_t wb_elems  = (size_t)N_DIM * K_DIM;  // 45,088,768
  const size_t cbb_elems = (size_t)NCODES * VECD;  // 262,144
  const size_t need =
      (xb_elems + wb_elems + cbb_elems) * sizeof(unsigned short); // ~172.5 MB

  if (ws_size >= need) {
    unsigned short* xb  = (unsigned short*)d_ws;
    unsigned short* wb  = xb + xb_elems;
    unsigned short* cbb = wb + wb_elems;
    cbcast_kernel<<<NCODES / 256, 256, 0, stream>>>(cb, cbb);
    dequant_cast_kernel<<<NVEC / 256, 256, 0, stream>>>(x, indices, cbb, xb, wb);
    gemm_bt_kernel<<<(M_DIM / 256) * (N_DIM / 256), 512, 6 * 8192 * 2, stream>>>(
        xb, wb, scales, out);
  } else {
    naive_kernel<<<dim3(N_DIM / 256, M_DIM), 256, 0, stream>>>(x, indices, cb,
                                                               scales, out);
  }
}